// Round 17
// baseline (387.470 us; speedup 1.0000x reference)
//
#include <hip/hip_runtime.h>
#include <cstdint>
#include <cstddef>

// GraphSAGE 3-layer, mean aggregation.
// R17: revert R16's counted-vmcnt pipeline (regressed; m139-style). Base =
// R15 (best, 349.7us). Evidence R11=R13=R14: gemm cost is per-STEP (latency
// quantum), not per-byte. So: BK=64 per step -> step count halves (NT 16->8,
// layer-0 4). Block re-tiled 128 rows x 64 cols to keep 48KB LDS dbuf
// (3 blocks/CU); grid 391x4=1564 (6.1 blocks/CU). Same total bytes staged,
// same MFMA count, same verified A-swizzle/W-frag-major layouts.
// agg (R4), single-plane W (R15), scan (R3), merged convert (R16) unchanged.

typedef __bf16 bf16x8 __attribute__((ext_vector_type(8)));
typedef __bf16 bf16x4 __attribute__((ext_vector_type(4)));
typedef float  f32x4  __attribute__((ext_vector_type(4)));

static inline size_t align_up(size_t x, size_t a) { return (x + a - 1) / a * a; }

__device__ __forceinline__ void gload_lds16(const void* g, void* l) {
    __builtin_amdgcn_global_load_lds(
        (const __attribute__((address_space(1))) void*)g,
        (__attribute__((address_space(3))) void*)l, 16, 0, 0);
}

__global__ void deg_kernel(const int* __restrict__ dst, int* __restrict__ deg, int E) {
    int i = blockIdx.x * blockDim.x + threadIdx.x;
    if (i < E) atomicAdd(&deg[dst[i]], 1);
}

// ---- 3-phase scan: deg -> rowptr (exclusive), cursor, inv_deg ----
__global__ void scan_a(const int* __restrict__ deg, int* __restrict__ blocksums, int n) {
    __shared__ int ts[256];
    int t = threadIdx.x;
    int base = blockIdx.x * 1024 + t * 4;
    int s = 0;
    #pragma unroll
    for (int j = 0; j < 4; ++j) if (base + j < n) s += deg[base + j];
    ts[t] = s;
    __syncthreads();
    #pragma unroll
    for (int off = 128; off >= 1; off >>= 1) {
        if (t < off) ts[t] += ts[t + off];
        __syncthreads();
    }
    if (t == 0) blocksums[blockIdx.x] = ts[0];
}

__global__ void scan_b(const int* __restrict__ blocksums, int* __restrict__ blockoff,
                       int NB, int* __restrict__ rowptr_n) {
    __shared__ int ts[256];
    int t = threadIdx.x;
    int v = (t < NB) ? blocksums[t] : 0;
    ts[t] = v;
    __syncthreads();
    for (int off = 1; off < 256; off <<= 1) {
        int u = (t >= off) ? ts[t - off] : 0;
        __syncthreads();
        ts[t] += u;
        __syncthreads();
    }
    if (t < NB) blockoff[t] = ts[t] - v;
    if (t == 255) *rowptr_n = ts[255];
}

__global__ void scan_c(const int* __restrict__ deg, const int* __restrict__ blockoff,
                       int* __restrict__ rowptr, int* __restrict__ cursor,
                       float* __restrict__ inv_deg, int n) {
    __shared__ int ts[256];
    int t = threadIdx.x;
    int base = blockIdx.x * 1024 + t * 4;
    int d[4];
    int s = 0;
    #pragma unroll
    for (int j = 0; j < 4; ++j) {
        d[j] = (base + j < n) ? deg[base + j] : 0;
        s += d[j];
    }
    ts[t] = s;
    __syncthreads();
    for (int off = 1; off < 256; off <<= 1) {
        int u = (t >= off) ? ts[t - off] : 0;
        __syncthreads();
        ts[t] += u;
        __syncthreads();
    }
    int ex = ts[t] - s + blockoff[blockIdx.x];
    #pragma unroll
    for (int j = 0; j < 4; ++j) {
        if (base + j < n) {
            rowptr[base + j] = ex;
            cursor[base + j] = ex;
            inv_deg[base + j] = d[j] > 0 ? 1.0f / (float)d[j] : 0.0f;
            ex += d[j];
        }
    }
}

__global__ void fill_kernel(const int* __restrict__ src, const int* __restrict__ dst,
                            int* __restrict__ cursor, int* __restrict__ csr, int E) {
    int i = blockIdx.x * blockDim.x + threadIdx.x;
    if (i < E) {
        int p = atomicAdd(&cursor[dst[i]], 1);
        csr[p] = src[i];
    }
}

// fp32 -> bf16 (RTNE) convert, 8 elems/thread.
__global__ void f32_to_bf16(const float* __restrict__ in, uint16_t* __restrict__ out, int count) {
    int i = (blockIdx.x * blockDim.x + threadIdx.x) * 8;
    if (i >= count) return;
    float4 v0 = *(const float4*)(in + i);
    float4 v1 = *(const float4*)(in + i + 4);
    bf16x8 o;
    o[0] = (__bf16)v0.x; o[1] = (__bf16)v0.y; o[2] = (__bf16)v0.z; o[3] = (__bf16)v0.w;
    o[4] = (__bf16)v1.x; o[5] = (__bf16)v1.y; o[6] = (__bf16)v1.z; o[7] = (__bf16)v1.w;
    *(bf16x8*)(out + i) = o;
}

__device__ inline void addq(float* a, uint32_t u0, uint32_t u1, uint32_t u2, uint32_t u3) {
    uint32_t u[4] = {u0, u1, u2, u3};
    #pragma unroll
    for (int i = 0; i < 4; ++i) {
        a[2 * i]     += __uint_as_float(u[i] << 16);
        a[2 * i + 1] += __uint_as_float(u[i] & 0xffff0000u);
    }
}

// bf16 gather aggregation: C/8 lanes per node, 16B (8 bf16) per lane.
template<int C>
__global__ void agg_bf16(const uint16_t* __restrict__ hb, const int* __restrict__ rowptr,
                         const int* __restrict__ csr, const float* __restrict__ inv_deg,
                         uint16_t* __restrict__ aggb, int n) {
    constexpr int LPN = C / 8;
    constexpr int NPB = 256 / LPN;
    int node = blockIdx.x * NPB + (int)(threadIdx.x / LPN);
    if (node >= n) return;
    int sub = threadIdx.x % LPN;
    int b = rowptr[node], e = rowptr[node + 1];
    float acc[8] = {0.f, 0.f, 0.f, 0.f, 0.f, 0.f, 0.f, 0.f};
    const uint4* h4 = (const uint4*)hb;
    int k = b;
    for (; k + 3 < e; k += 4) {
        int s0 = csr[k], s1 = csr[k + 1], s2 = csr[k + 2], s3 = csr[k + 3];
        uint4 q0 = h4[(size_t)s0 * LPN + sub];
        uint4 q1 = h4[(size_t)s1 * LPN + sub];
        uint4 q2 = h4[(size_t)s2 * LPN + sub];
        uint4 q3 = h4[(size_t)s3 * LPN + sub];
        addq(acc, q0.x, q0.y, q0.z, q0.w);
        addq(acc, q1.x, q1.y, q1.z, q1.w);
        addq(acc, q2.x, q2.y, q2.z, q2.w);
        addq(acc, q3.x, q3.y, q3.z, q3.w);
    }
    for (; k < e; ++k) {
        uint4 q = h4[(size_t)csr[k] * LPN + sub];
        addq(acc, q.x, q.y, q.z, q.w);
    }
    float id = inv_deg[node];
    bf16x8 o;
    #pragma unroll
    for (int j = 0; j < 8; ++j) o[j] = (__bf16)(acc[j] * id);
    *(bf16x8*)(aggb + (size_t)node * C + sub * 8) = o;
}

// Pre-convert all three W = [Wl; Wr] into per-32k-step FRAGMENT-MAJOR bf16
// planes (hi only). Step s, plane 16KB: col-group cg (0..15) x lane l (0..63)
// x 16B; (cg,l) 16B = cols cg*16+(l&15), k-quad (l>>4)*8..+7.
__global__ void convert_w_all(const float* __restrict__ Wl0, const float* __restrict__ Wr0,
                              uint8_t* __restrict__ Wp0,
                              const float* __restrict__ Wl1, const float* __restrict__ Wr1,
                              uint8_t* __restrict__ Wp1,
                              const float* __restrict__ Wl2, const float* __restrict__ Wr2,
                              uint8_t* __restrict__ Wp2) {
    int bid = blockIdx.x;
    const float *Wl, *Wr;
    uint8_t* Wpre;
    int K1, kbase;
    if (bid < 64)       { Wl = Wl0; Wr = Wr0; Wpre = Wp0; K1 = 128; kbase = bid * 4; }
    else if (bid < 192) { Wl = Wl1; Wr = Wr1; Wpre = Wp1; K1 = 256; kbase = (bid - 64) * 4; }
    else                { Wl = Wl2; Wr = Wr2; Wpre = Wp2; K1 = 256; kbase = (bid - 192) * 4; }
    int c = threadIdx.x;
    bf16x4 hi4;
    #pragma unroll
    for (int j = 0; j < 4; ++j) {
        int k = kbase + j;
        float w = (k < K1) ? Wl[(size_t)k * 256 + c] : Wr[(size_t)(k - K1) * 256 + c];
        hi4[j] = (__bf16)w;
    }
    int s = kbase >> 5;
    int kk = kbase & 31;
    int lane = (c & 15) + ((kk >> 3) << 4);
    uint32_t byte = (uint32_t)(c >> 4) * 1024 + (uint32_t)lane * 16 + (uint32_t)(kk & 7) * 2;
    *(bf16x4*)(Wpre + (size_t)s * 16384 + byte) = hi4;
}

__device__ inline uint16_t f2bf(float f) {
    __bf16 h = (__bf16)f;
    union { __bf16 b; uint16_t u; } c;
    c.b = h;
    return c.u;
}

// Fused GEMM: out = relu([A1 | A2] @ W + bias), A row-major bf16, W bf16.
// Block = 128 rows x 64 cols (bid>>2 = row panel, bid&3 = col quarter);
// 4 waves: wave w rows (w&1)*64, cols (w>>1)*32. BK=64 per step:
// stage 24KB (A 16K: 16x1KB blocks over 2 k-halves; W 8K: 8x1KB), 6 gloads/
// thread; ds_read + 16 MFMA; ONE barrier. LDS 2x24KB = 48KB (3 blocks/CU).
template<int K1>
__global__ __launch_bounds__(256, 3)
void gemm_mfma(const uint16_t* __restrict__ A1, const uint16_t* __restrict__ A2,
               const uint8_t* __restrict__ Wpre, const float* __restrict__ bias,
               float* __restrict__ out, uint16_t* __restrict__ outb, int n) {
    constexpr int NT = K1 / 32;        // 64-k steps total (2*K1/64): 4 or 8
    constexpr int SH = K1 / 64;        // steps in the A1 half: 2 or 4
    __shared__ __align__(16) uint8_t ldsA[2][16384];  // [buf][kk*8KB + row*64B]
    __shared__ __align__(16) uint8_t ldsW[2][8192];   // [buf][kk*4KB + cg*1KB]

    const int tid = threadIdx.x;
    const int l = tid & 63;
    const int w = tid >> 6;
    const int lr = l & 15;
    const int lg = l >> 4;
    const int row0 = (blockIdx.x >> 2) * 128;
    const int cq = blockIdx.x & 3;       // col quarter (64 cols)
    const int wr = w & 1;                // wave row half (64 rows)
    const int cw = w >> 1;               // wave col half (32 cols)

    f32x4 acc[4][2];
    #pragma unroll
    for (int mt = 0; mt < 4; ++mt)
        #pragma unroll
        for (int nt = 0; nt < 2; ++nt)
            acc[mt][nt] = (f32x4)(0.f);

    // A fragment read offsets (swizzled): row r = wr*64+mt*16+lr,
    // slot = lg ^ ((r>>1)&3) = lg ^ ((lr>>1)&3).
    const int key = (lr >> 1) & 3;
    uint32_t abyte[4];
    #pragma unroll
    for (int mt = 0; mt < 4; ++mt)
        abyte[mt] = (uint32_t)((wr * 64 + mt * 16 + lr) * 64 + ((lg ^ key) << 4));
    // W fragment read offsets (fragment-major, conflict-free): local cg = cw*2+nt
    uint32_t wrbyte[2];
    #pragma unroll
    for (int nt = 0; nt < 2; ++nt)
        wrbyte[nt] = (uint32_t)((cw * 2 + nt) * 1024 + l * 16);

    // staging per 64-k step: A 16 blocks (b = kk*8+rg), W 8 blocks (b = kk*4+cgl);
    // wave w stages A {4w..4w+3}, W {2w,2w+1}. All dsts wave-uniform 1KB.
    auto stage = [&](int s, int buf) {
        const uint16_t* __restrict__ A = (s < SH) ? A1 : A2;
        int kl = ((s < SH) ? s : s - SH) * 64;
        #pragma unroll
        for (int i = 0; i < 4; ++i) {
            int b = w * 4 + i;                     // 0..15
            int kk = b >> 3;
            int rg = b & 7;
            int r = rg * 16 + (l >> 2);            // row 0..127
            int kq = (l & 3) ^ ((r >> 1) & 3);     // pre-swizzled source k-quad
            gload_lds16(A + (size_t)(row0 + r) * K1 + kl + kk * 32 + kq * 8,
                        &ldsA[buf][b * 1024]);
        }
        #pragma unroll
        for (int i = 0; i < 2; ++i) {
            int b = w * 2 + i;                     // 0..7
            int kk = b >> 2;
            int cgl = b & 3;
            const uint8_t* src = Wpre + (size_t)(s * 2 + kk) * 16384
                               + (size_t)cq * 4096 + (size_t)cgl * 1024 + (size_t)l * 16;
            gload_lds16(src, &ldsW[buf][b * 1024]);
        }
    };

    auto domfma = [&](int buf) {
        #pragma unroll
        for (int kk = 0; kk < 2; ++kk) {
            bf16x8 bh[2];
            #pragma unroll
            for (int nt = 0; nt < 2; ++nt)
                bh[nt] = *(const bf16x8*)(&ldsW[buf][kk * 4096 + wrbyte[nt]]);
            #pragma unroll
            for (int mt = 0; mt < 4; ++mt) {
                bf16x8 a = *(const bf16x8*)(&ldsA[buf][kk * 8192 + abyte[mt]]);
                #pragma unroll
                for (int nt = 0; nt < 2; ++nt)
                    acc[mt][nt] = __builtin_amdgcn_mfma_f32_16x16x32_bf16(a, bh[nt], acc[mt][nt], 0, 0, 0);
            }
        }
    };

    stage(0, 0);
    __syncthreads();
    #pragma unroll 1
    for (int s = 0; s < NT; ++s) {
        int buf = s & 1;
        if (s + 1 < NT) stage(s + 1, buf ^ 1);   // in flight over MFMAs
        domfma(buf);
        __syncthreads();
    }

    // epilogue: D row = row0 + wr*64 + mt*16 + lg*4 + rr,
    //           col = cq*64 + cw*32 + nt*16 + lr (m89-verified)
    #pragma unroll
    for (int nt = 0; nt < 2; ++nt) {
        int col = cq * 64 + cw * 32 + nt * 16 + lr;
        float bv = bias[col];
        #pragma unroll
        for (int mt = 0; mt < 4; ++mt) {
            #pragma unroll
            for (int rr = 0; rr < 4; ++rr) {
                int grow = row0 + wr * 64 + mt * 16 + lg * 4 + rr;
                if (grow < n) {
                    float v = fmaxf(acc[mt][nt][rr] + bv, 0.f);
                    if (out)  out[(size_t)grow * 256 + col] = v;
                    if (outb) outb[(size_t)grow * 256 + col] = f2bf(v);
                }
            }
        }
    }
}

extern "C" void kernel_launch(void* const* d_in, const int* in_sizes, int n_in,
                              void* d_out, int out_size, void* d_ws, size_t ws_size,
                              hipStream_t stream) {
    const float* x   = (const float*)d_in[0];
    const int* edge  = (const int*)d_in[1];
    const float* Wl0 = (const float*)d_in[2];
    const float* bl0 = (const float*)d_in[3];
    const float* Wr0 = (const float*)d_in[4];
    const float* Wl1 = (const float*)d_in[5];
    const float* bl1 = (const float*)d_in[6];
    const float* Wr1 = (const float*)d_in[7];
    const float* Wl2 = (const float*)d_in[8];
    const float* bl2 = (const float*)d_in[9];
    const float* Wr2 = (const float*)d_in[10];

    int n = in_sizes[0] / 128;   // 50000
    int E = in_sizes[1] / 2;     // 800000
    int npad = n + 128;
    const int* src = edge;
    const int* dst = edge + E;

    char* wptr = (char*)d_ws;
    auto alloc = [&](size_t bytes) { char* p = wptr; wptr += align_up(bytes, 256); return p; };
    int*      deg    = (int*)alloc((size_t)n * 4);
    int*      rowptr = (int*)alloc(((size_t)n + 1) * 4);
    int*      cursor = (int*)alloc((size_t)n * 4);
    int*      csr    = (int*)alloc((size_t)E * 4);
    float*    invd   = (float*)alloc((size_t)n * 4);
    int*      bsums  = (int*)alloc(256 * 4);
    int*      boff   = (int*)alloc(256 * 4);
    uint8_t*  Wp0    = (uint8_t*)alloc(8 * 16384);    // 8 x 16KB planes
    uint8_t*  Wp1    = (uint8_t*)alloc(16 * 16384);   // 16 x 16KB planes
    uint8_t*  Wp2    = (uint8_t*)alloc(16 * 16384);
    uint16_t* xb     = (uint16_t*)alloc((size_t)npad * 128 * 2);
    uint16_t* aggb   = (uint16_t*)alloc((size_t)npad * 256 * 2);
    uint16_t* h0b    = (uint16_t*)alloc((size_t)npad * 256 * 2);
    uint16_t* h1b    = (uint16_t*)alloc((size_t)npad * 256 * 2);

    int NB = (n + 1023) / 1024;
    hipMemsetAsync(deg, 0, (size_t)n * 4, stream);
    deg_kernel<<<(E + 255) / 256, 256, 0, stream>>>(dst, deg, E);
    scan_a<<<NB, 256, 0, stream>>>(deg, bsums, n);
    scan_b<<<1, 256, 0, stream>>>(bsums, boff, NB, rowptr + n);
    scan_c<<<NB, 256, 0, stream>>>(deg, boff, rowptr, cursor, invd, n);
    fill_kernel<<<(E + 255) / 256, 256, 0, stream>>>(src, dst, cursor, csr, E);

    convert_w_all<<<320, 256, 0, stream>>>(Wl0, Wr0, Wp0, Wl1, Wr1, Wp1, Wl2, Wr2, Wp2);

    int cx = n * 128;
    f32_to_bf16<<<(cx / 8 + 255) / 256, 256, 0, stream>>>(x, xb, cx);

    int gemm_grid = ((n + 127) / 128) * 4;   // 1564
    // layer 0: C=128 -> 256
    agg_bf16<128><<<(n + 15) / 16, 256, 0, stream>>>(xb, rowptr, csr, invd, aggb, n);
    gemm_mfma<128><<<gemm_grid, 256, 0, stream>>>(aggb, xb, Wp0, bl0, (float*)nullptr, h0b, n);
    // layer 1: 256 -> 256
    agg_bf16<256><<<(n + 7) / 8, 256, 0, stream>>>(h0b, rowptr, csr, invd, aggb, n);
    gemm_mfma<256><<<gemm_grid, 256, 0, stream>>>(aggb, h0b, Wp1, bl1, (float*)nullptr, h1b, n);
    // layer 2: 256 -> 256 (fp32 output to d_out)
    agg_bf16<256><<<(n + 7) / 8, 256, 0, stream>>>(h1b, rowptr, csr, invd, aggb, n);
    gemm_mfma<256><<<gemm_grid, 256, 0, stream>>>(aggb, h1b, Wp2, bl2, (float*)d_out, (uint16_t*)nullptr, n);
}

// Round 18
// 303.470 us; speedup vs baseline: 1.2768x; 1.2768x over previous
//
#include <hip/hip_runtime.h>
#include <cstdint>
#include <cstddef>

// GraphSAGE 3-layer, mean aggregation.
// R18: revert R17 (BK=64 re-tile doubled A-staging duplication; gemm cost
// tracks staged volume -> R15 structure restored exactly). New: CSR fill via
// RANK-FROM-DEGREE. fill_kernel was 57us/call (800k atomicAdd-with-return on
// random cursors, 52MB of dirty-line writeback). deg pass now stores each
// edge's rank (the atomic's return value, free); after the scan, fill is
// atomic-free: csr[rowptr[dst]+rank] = src (pure scatter into L2-resident
// 3.2MB). cursor array deleted.
// Kept: 128x128 BK=32 gemm + single-plane W (R15, 349.7us best), bf16 agg
// (R4), 3-phase scan (R3), merged convert_w (R16).

typedef __bf16 bf16x8 __attribute__((ext_vector_type(8)));
typedef __bf16 bf16x4 __attribute__((ext_vector_type(4)));
typedef float  f32x4  __attribute__((ext_vector_type(4)));

static inline size_t align_up(size_t x, size_t a) { return (x + a - 1) / a * a; }

__device__ __forceinline__ void gload_lds16(const void* g, void* l) {
    __builtin_amdgcn_global_load_lds(
        (const __attribute__((address_space(1))) void*)g,
        (__attribute__((address_space(3))) void*)l, 16, 0, 0);
}

// deg count + per-edge rank (atomic return value).
__global__ void deg_rank_kernel(const int* __restrict__ dst, int* __restrict__ deg,
                                int* __restrict__ rank, int E) {
    int i = blockIdx.x * blockDim.x + threadIdx.x;
    if (i < E) rank[i] = atomicAdd(&deg[dst[i]], 1);
}

// ---- 3-phase scan: deg -> rowptr (exclusive), inv_deg ----
__global__ void scan_a(const int* __restrict__ deg, int* __restrict__ blocksums, int n) {
    __shared__ int ts[256];
    int t = threadIdx.x;
    int base = blockIdx.x * 1024 + t * 4;
    int s = 0;
    #pragma unroll
    for (int j = 0; j < 4; ++j) if (base + j < n) s += deg[base + j];
    ts[t] = s;
    __syncthreads();
    #pragma unroll
    for (int off = 128; off >= 1; off >>= 1) {
        if (t < off) ts[t] += ts[t + off];
        __syncthreads();
    }
    if (t == 0) blocksums[blockIdx.x] = ts[0];
}

__global__ void scan_b(const int* __restrict__ blocksums, int* __restrict__ blockoff,
                       int NB, int* __restrict__ rowptr_n) {
    __shared__ int ts[256];
    int t = threadIdx.x;
    int v = (t < NB) ? blocksums[t] : 0;
    ts[t] = v;
    __syncthreads();
    for (int off = 1; off < 256; off <<= 1) {
        int u = (t >= off) ? ts[t - off] : 0;
        __syncthreads();
        ts[t] += u;
        __syncthreads();
    }
    if (t < NB) blockoff[t] = ts[t] - v;
    if (t == 255) *rowptr_n = ts[255];
}

__global__ void scan_c(const int* __restrict__ deg, const int* __restrict__ blockoff,
                       int* __restrict__ rowptr, float* __restrict__ inv_deg, int n) {
    __shared__ int ts[256];
    int t = threadIdx.x;
    int base = blockIdx.x * 1024 + t * 4;
    int d[4];
    int s = 0;
    #pragma unroll
    for (int j = 0; j < 4; ++j) {
        d[j] = (base + j < n) ? deg[base + j] : 0;
        s += d[j];
    }
    ts[t] = s;
    __syncthreads();
    for (int off = 1; off < 256; off <<= 1) {
        int u = (t >= off) ? ts[t - off] : 0;
        __syncthreads();
        ts[t] += u;
        __syncthreads();
    }
    int ex = ts[t] - s + blockoff[blockIdx.x];
    #pragma unroll
    for (int j = 0; j < 4; ++j) {
        if (base + j < n) {
            rowptr[base + j] = ex;
            inv_deg[base + j] = d[j] > 0 ? 1.0f / (float)d[j] : 0.0f;
            ex += d[j];
        }
    }
}

// atomic-free CSR fill: pos = rowptr[dst] + rank (precomputed).
__global__ void fill_kernel(const int* __restrict__ src, const int* __restrict__ dst,
                            const int* __restrict__ rowptr, const int* __restrict__ rank,
                            int* __restrict__ csr, int E) {
    int i = blockIdx.x * blockDim.x + threadIdx.x;
    if (i < E) csr[rowptr[dst[i]] + rank[i]] = src[i];
}

// fp32 -> bf16 (RTNE) convert, 8 elems/thread.
__global__ void f32_to_bf16(const float* __restrict__ in, uint16_t* __restrict__ out, int count) {
    int i = (blockIdx.x * blockDim.x + threadIdx.x) * 8;
    if (i >= count) return;
    float4 v0 = *(const float4*)(in + i);
    float4 v1 = *(const float4*)(in + i + 4);
    bf16x8 o;
    o[0] = (__bf16)v0.x; o[1] = (__bf16)v0.y; o[2] = (__bf16)v0.z; o[3] = (__bf16)v0.w;
    o[4] = (__bf16)v1.x; o[5] = (__bf16)v1.y; o[6] = (__bf16)v1.z; o[7] = (__bf16)v1.w;
    *(bf16x8*)(out + i) = o;
}

__device__ inline void addq(float* a, uint32_t u0, uint32_t u1, uint32_t u2, uint32_t u3) {
    uint32_t u[4] = {u0, u1, u2, u3};
    #pragma unroll
    for (int i = 0; i < 4; ++i) {
        a[2 * i]     += __uint_as_float(u[i] << 16);
        a[2 * i + 1] += __uint_as_float(u[i] & 0xffff0000u);
    }
}

// bf16 gather aggregation: C/8 lanes per node, 16B (8 bf16) per lane.
template<int C>
__global__ void agg_bf16(const uint16_t* __restrict__ hb, const int* __restrict__ rowptr,
                         const int* __restrict__ csr, const float* __restrict__ inv_deg,
                         uint16_t* __restrict__ aggb, int n) {
    constexpr int LPN = C / 8;
    constexpr int NPB = 256 / LPN;
    int node = blockIdx.x * NPB + (int)(threadIdx.x / LPN);
    if (node >= n) return;
    int sub = threadIdx.x % LPN;
    int b = rowptr[node], e = rowptr[node + 1];
    float acc[8] = {0.f, 0.f, 0.f, 0.f, 0.f, 0.f, 0.f, 0.f};
    const uint4* h4 = (const uint4*)hb;
    int k = b;
    for (; k + 3 < e; k += 4) {
        int s0 = csr[k], s1 = csr[k + 1], s2 = csr[k + 2], s3 = csr[k + 3];
        uint4 q0 = h4[(size_t)s0 * LPN + sub];
        uint4 q1 = h4[(size_t)s1 * LPN + sub];
        uint4 q2 = h4[(size_t)s2 * LPN + sub];
        uint4 q3 = h4[(size_t)s3 * LPN + sub];
        addq(acc, q0.x, q0.y, q0.z, q0.w);
        addq(acc, q1.x, q1.y, q1.z, q1.w);
        addq(acc, q2.x, q2.y, q2.z, q2.w);
        addq(acc, q3.x, q3.y, q3.z, q3.w);
    }
    for (; k < e; ++k) {
        uint4 q = h4[(size_t)csr[k] * LPN + sub];
        addq(acc, q.x, q.y, q.z, q.w);
    }
    float id = inv_deg[node];
    bf16x8 o;
    #pragma unroll
    for (int j = 0; j < 8; ++j) o[j] = (__bf16)(acc[j] * id);
    *(bf16x8*)(aggb + (size_t)node * C + sub * 8) = o;
}

// Pre-convert all three W = [Wl; Wr] into per-k-step FRAGMENT-MAJOR bf16
// planes (hi only). Step s (BK=32), plane 16KB: col-group cg (0..15) x lane
// l (0..63) x 16B; (cg,l) 16B = cols cg*16+(l&15), k-quad (l>>4)*8..+7.
__global__ void convert_w_all(const float* __restrict__ Wl0, const float* __restrict__ Wr0,
                              uint8_t* __restrict__ Wp0,
                              const float* __restrict__ Wl1, const float* __restrict__ Wr1,
                              uint8_t* __restrict__ Wp1,
                              const float* __restrict__ Wl2, const float* __restrict__ Wr2,
                              uint8_t* __restrict__ Wp2) {
    int bid = blockIdx.x;
    const float *Wl, *Wr;
    uint8_t* Wpre;
    int K1, kbase;
    if (bid < 64)       { Wl = Wl0; Wr = Wr0; Wpre = Wp0; K1 = 128; kbase = bid * 4; }
    else if (bid < 192) { Wl = Wl1; Wr = Wr1; Wpre = Wp1; K1 = 256; kbase = (bid - 64) * 4; }
    else                { Wl = Wl2; Wr = Wr2; Wpre = Wp2; K1 = 256; kbase = (bid - 192) * 4; }
    int c = threadIdx.x;
    bf16x4 hi4;
    #pragma unroll
    for (int j = 0; j < 4; ++j) {
        int k = kbase + j;
        float w = (k < K1) ? Wl[(size_t)k * 256 + c] : Wr[(size_t)(k - K1) * 256 + c];
        hi4[j] = (__bf16)w;
    }
    int s = kbase >> 5;
    int kk = kbase & 31;
    int lane = (c & 15) + ((kk >> 3) << 4);
    uint32_t byte = (uint32_t)(c >> 4) * 1024 + (uint32_t)lane * 16 + (uint32_t)(kk & 7) * 2;
    *(bf16x4*)(Wpre + (size_t)s * 16384 + byte) = hi4;
}

__device__ inline uint16_t f2bf(float f) {
    __bf16 h = (__bf16)f;
    union { __bf16 b; uint16_t u; } c;
    c.b = h;
    return c.u;
}

// Fused GEMM (R15-proven): out = relu([A1 | A2] @ W + bias), A/W bf16.
// 128 rows x 128 cols per block (bid>>1 = row panel, bid&1 = col half);
// 4 waves, wave w: rows (w&1)*64, cols (w>>1)*64. m97 pipeline: per step
// stage(s+1, buf^1) = A 8KB + W 8KB via global_load_lds (4 x 16B/thread),
// then ds_read + 16 MFMA, ONE barrier. LDS 2x16KB = 32KB.
template<int K1>
__global__ __launch_bounds__(256, 3)
void gemm_mfma(const uint16_t* __restrict__ A1, const uint16_t* __restrict__ A2,
               const uint8_t* __restrict__ Wpre, const float* __restrict__ bias,
               float* __restrict__ out, uint16_t* __restrict__ outb, int n) {
    constexpr int S1 = K1 / 32;
    constexpr int NT = 2 * S1;          // 8 or 16
    __shared__ __align__(16) uint8_t ldsA[2][8192];   // 128 rows x 64B
    __shared__ __align__(16) uint8_t ldsW[2][8192];   // 128 cols x 64B (frag-major)

    const int tid = threadIdx.x;
    const int l = tid & 63;
    const int w = tid >> 6;
    const int lr = l & 15;
    const int lg = l >> 4;
    const int row0 = (blockIdx.x >> 1) * 128;
    const int cb = blockIdx.x & 1;       // col half (128 cols)
    const int wr = w & 1;                // wave row half (64 rows)
    const int cw = w >> 1;               // wave col group (64 cols)

    f32x4 acc[4][4];
    #pragma unroll
    for (int mt = 0; mt < 4; ++mt)
        #pragma unroll
        for (int nt = 0; nt < 4; ++nt)
            acc[mt][nt] = (f32x4)(0.f);

    // A fragment read offsets (swizzled): row r = wr*64+mt*16+lr,
    // slot = lg ^ ((r>>1)&3) = lg ^ ((lr>>1)&3).
    const int key = (lr >> 1) & 3;
    uint32_t abyte[4];
    #pragma unroll
    for (int mt = 0; mt < 4; ++mt)
        abyte[mt] = (uint32_t)((wr * 64 + mt * 16 + lr) * 64 + ((lg ^ key) << 4));
    // W fragment read offsets (fragment-major, conflict-free): local cg = cw*4+nt
    uint32_t wrbyte[4];
    #pragma unroll
    for (int nt = 0; nt < 4; ++nt)
        wrbyte[nt] = (uint32_t)((cw * 4 + nt) * 1024 + l * 16);

    // staging: 16 x 1KB wave-uniform blocks per step; wave w stages
    // A blocks {2w,2w+1}, W blocks {2w,2w+1}.
    auto stage = [&](int s, int buf) {
        const uint16_t* __restrict__ A = (s < S1) ? A1 : A2;
        int kl = ((s < S1) ? s : s - S1) * 32;
        #pragma unroll
        for (int i = 0; i < 2; ++i) {
            int b = w * 2 + i;                     // A block 0..7
            int r = b * 16 + (l >> 2);             // row 0..127
            int kq = (l & 3) ^ ((r >> 1) & 3);     // pre-swizzled source k-quad
            gload_lds16(A + (size_t)(row0 + r) * K1 + kl + kq * 8,
                        &ldsA[buf][b * 1024]);
        }
        const uint8_t* __restrict__ Ws = Wpre + (size_t)s * 16384 + (size_t)cb * 8192;
        #pragma unroll
        for (int i = 0; i < 2; ++i) {
            int b = w * 2 + i;                     // W block 0..7
            gload_lds16(Ws + b * 1024 + l * 16, &ldsW[buf][b * 1024]);
        }
    };

    auto domfma = [&](int buf) {
        bf16x8 bh[4];
        #pragma unroll
        for (int nt = 0; nt < 4; ++nt)
            bh[nt] = *(const bf16x8*)(&ldsW[buf][wrbyte[nt]]);
        #pragma unroll
        for (int mt = 0; mt < 4; ++mt) {
            bf16x8 a = *(const bf16x8*)(&ldsA[buf][abyte[mt]]);
            #pragma unroll
            for (int nt = 0; nt < 4; ++nt)
                acc[mt][nt] = __builtin_amdgcn_mfma_f32_16x16x32_bf16(a, bh[nt], acc[mt][nt], 0, 0, 0);
        }
    };

    stage(0, 0);
    __syncthreads();
    #pragma unroll 1
    for (int s = 0; s < NT; ++s) {
        int buf = s & 1;
        if (s + 1 < NT) stage(s + 1, buf ^ 1);   // in flight over MFMAs
        domfma(buf);
        __syncthreads();
    }

    // epilogue: D row = row0 + wr*64 + mt*16 + lg*4 + rr,
    //           col = cb*128 + cw*64 + nt*16 + lr (m89-verified)
    #pragma unroll
    for (int nt = 0; nt < 4; ++nt) {
        int col = cb * 128 + cw * 64 + nt * 16 + lr;
        float bv = bias[col];
        #pragma unroll
        for (int mt = 0; mt < 4; ++mt) {
            #pragma unroll
            for (int rr = 0; rr < 4; ++rr) {
                int grow = row0 + wr * 64 + mt * 16 + lg * 4 + rr;
                if (grow < n) {
                    float v = fmaxf(acc[mt][nt][rr] + bv, 0.f);
                    if (out)  out[(size_t)grow * 256 + col] = v;
                    if (outb) outb[(size_t)grow * 256 + col] = f2bf(v);
                }
            }
        }
    }
}

extern "C" void kernel_launch(void* const* d_in, const int* in_sizes, int n_in,
                              void* d_out, int out_size, void* d_ws, size_t ws_size,
                              hipStream_t stream) {
    const float* x   = (const float*)d_in[0];
    const int* edge  = (const int*)d_in[1];
    const float* Wl0 = (const float*)d_in[2];
    const float* bl0 = (const float*)d_in[3];
    const float* Wr0 = (const float*)d_in[4];
    const float* Wl1 = (const float*)d_in[5];
    const float* bl1 = (const float*)d_in[6];
    const float* Wr1 = (const float*)d_in[7];
    const float* Wl2 = (const float*)d_in[8];
    const float* bl2 = (const float*)d_in[9];
    const float* Wr2 = (const float*)d_in[10];

    int n = in_sizes[0] / 128;   // 50000
    int E = in_sizes[1] / 2;     // 800000
    int npad = n + 128;
    const int* src = edge;
    const int* dst = edge + E;

    char* wptr = (char*)d_ws;
    auto alloc = [&](size_t bytes) { char* p = wptr; wptr += align_up(bytes, 256); return p; };
    int*      deg    = (int*)alloc((size_t)n * 4);
    int*      rowptr = (int*)alloc(((size_t)n + 1) * 4);
    int*      rank   = (int*)alloc((size_t)E * 4);
    int*      csr    = (int*)alloc((size_t)E * 4);
    float*    invd   = (float*)alloc((size_t)n * 4);
    int*      bsums  = (int*)alloc(256 * 4);
    int*      boff   = (int*)alloc(256 * 4);
    uint8_t*  Wp0    = (uint8_t*)alloc(8 * 16384);    // 8 steps x 16KB
    uint8_t*  Wp1    = (uint8_t*)alloc(16 * 16384);   // 16 steps x 16KB
    uint8_t*  Wp2    = (uint8_t*)alloc(16 * 16384);
    uint16_t* xb     = (uint16_t*)alloc((size_t)npad * 128 * 2);
    uint16_t* aggb   = (uint16_t*)alloc((size_t)npad * 256 * 2);
    uint16_t* h0b    = (uint16_t*)alloc((size_t)npad * 256 * 2);
    uint16_t* h1b    = (uint16_t*)alloc((size_t)npad * 256 * 2);

    int NB = (n + 1023) / 1024;
    hipMemsetAsync(deg, 0, (size_t)n * 4, stream);
    deg_rank_kernel<<<(E + 255) / 256, 256, 0, stream>>>(dst, deg, rank, E);
    scan_a<<<NB, 256, 0, stream>>>(deg, bsums, n);
    scan_b<<<1, 256, 0, stream>>>(bsums, boff, NB, rowptr + n);
    scan_c<<<NB, 256, 0, stream>>>(deg, boff, rowptr, invd, n);
    fill_kernel<<<(E + 255) / 256, 256, 0, stream>>>(src, dst, rowptr, rank, csr, E);

    convert_w_all<<<320, 256, 0, stream>>>(Wl0, Wr0, Wp0, Wl1, Wr1, Wp1, Wl2, Wr2, Wp2);

    int cx = n * 128;
    f32_to_bf16<<<(cx / 8 + 255) / 256, 256, 0, stream>>>(x, xb, cx);

    int gemm_grid = ((n + 127) / 128) * 2;   // 782
    // layer 0: C=128 -> 256
    agg_bf16<128><<<(n + 15) / 16, 256, 0, stream>>>(xb, rowptr, csr, invd, aggb, n);
    gemm_mfma<128><<<gemm_grid, 256, 0, stream>>>(aggb, xb, Wp0, bl0, (float*)nullptr, h0b, n);
    // layer 1: 256 -> 256
    agg_bf16<256><<<(n + 7) / 8, 256, 0, stream>>>(h0b, rowptr, csr, invd, aggb, n);
    gemm_mfma<256><<<gemm_grid, 256, 0, stream>>>(aggb, h0b, Wp1, bl1, (float*)nullptr, h1b, n);
    // layer 2: 256 -> 256 (fp32 output to d_out)
    agg_bf16<256><<<(n + 7) / 8, 256, 0, stream>>>(h1b, rowptr, csr, invd, aggb, n);
    gemm_mfma<256><<<gemm_grid, 256, 0, stream>>>(aggb, h1b, Wp2, bl2, (float*)d_out, (uint16_t*)nullptr, n);
}

// Round 19
// 297.300 us; speedup vs baseline: 1.3033x; 1.0208x over previous
//
#include <hip/hip_runtime.h>
#include <cstdint>
#include <cstddef>

// GraphSAGE 3-layer, mean aggregation.
// R19: two changes on R18 (303.5us best).
// 1) agg 8-way neighbor unroll: 16 rows in flight/wave (was 8). Discriminates
//    latency-undercovered (helps) vs MSHR-bound (no change; then ~290us is the
//    practical floor: agg FETCH=175MB/dispatch = compulsory per-XCD traffic,
//    measured = predicted within 1%). Summation order unchanged -> bit-identical.
// 2) independent prep (deg_rank | f32_to_bf16 | convert_w) fused into one
//    block-ranged dispatch: cvt+convert hide under deg_rank's atomic latency.
// Kept: rank-from-degree fill (R18), 128x128 BK=32 single-plane-W gemm (R15),
// 3-phase scan (R3).

typedef __bf16 bf16x8 __attribute__((ext_vector_type(8)));
typedef __bf16 bf16x4 __attribute__((ext_vector_type(4)));
typedef float  f32x4  __attribute__((ext_vector_type(4)));

static inline size_t align_up(size_t x, size_t a) { return (x + a - 1) / a * a; }

__device__ __forceinline__ void gload_lds16(const void* g, void* l) {
    __builtin_amdgcn_global_load_lds(
        (const __attribute__((address_space(1))) void*)g,
        (__attribute__((address_space(3))) void*)l, 16, 0, 0);
}

// ---- fused prep: [0,nb1) deg+rank | [nb1,nb1+nb2) x->bf16 | rest convert_w ----
__global__ void prep_all(const int* __restrict__ dst, int* __restrict__ deg,
                         int* __restrict__ rank, int E, int nb1,
                         const float* __restrict__ x, uint16_t* __restrict__ xb,
                         int cx, int nb2,
                         const float* __restrict__ Wl0, const float* __restrict__ Wr0,
                         uint8_t* __restrict__ Wp0,
                         const float* __restrict__ Wl1, const float* __restrict__ Wr1,
                         uint8_t* __restrict__ Wp1,
                         const float* __restrict__ Wl2, const float* __restrict__ Wr2,
                         uint8_t* __restrict__ Wp2) {
    int bid = blockIdx.x;
    if (bid < nb1) {
        int i = bid * 256 + threadIdx.x;
        if (i < E) rank[i] = atomicAdd(&deg[dst[i]], 1);
        return;
    }
    bid -= nb1;
    if (bid < nb2) {
        int i = (bid * 256 + threadIdx.x) * 8;
        if (i >= cx) return;
        float4 v0 = *(const float4*)(x + i);
        float4 v1 = *(const float4*)(x + i + 4);
        bf16x8 o;
        o[0] = (__bf16)v0.x; o[1] = (__bf16)v0.y; o[2] = (__bf16)v0.z; o[3] = (__bf16)v0.w;
        o[4] = (__bf16)v1.x; o[5] = (__bf16)v1.y; o[6] = (__bf16)v1.z; o[7] = (__bf16)v1.w;
        *(bf16x8*)(xb + i) = o;
        return;
    }
    bid -= nb2;   // 0..319
    const float *Wl, *Wr;
    uint8_t* Wpre;
    int K1, kbase;
    if (bid < 64)       { Wl = Wl0; Wr = Wr0; Wpre = Wp0; K1 = 128; kbase = bid * 4; }
    else if (bid < 192) { Wl = Wl1; Wr = Wr1; Wpre = Wp1; K1 = 256; kbase = (bid - 64) * 4; }
    else                { Wl = Wl2; Wr = Wr2; Wpre = Wp2; K1 = 256; kbase = (bid - 192) * 4; }
    int c = threadIdx.x;
    bf16x4 hi4;
    #pragma unroll
    for (int j = 0; j < 4; ++j) {
        int k = kbase + j;
        float w = (k < K1) ? Wl[(size_t)k * 256 + c] : Wr[(size_t)(k - K1) * 256 + c];
        hi4[j] = (__bf16)w;
    }
    int s = kbase >> 5;
    int kk = kbase & 31;
    int lane = (c & 15) + ((kk >> 3) << 4);
    uint32_t byte = (uint32_t)(c >> 4) * 1024 + (uint32_t)lane * 16 + (uint32_t)(kk & 7) * 2;
    *(bf16x4*)(Wpre + (size_t)s * 16384 + byte) = hi4;
}

// ---- 3-phase scan: deg -> rowptr (exclusive), inv_deg ----
__global__ void scan_a(const int* __restrict__ deg, int* __restrict__ blocksums, int n) {
    __shared__ int ts[256];
    int t = threadIdx.x;
    int base = blockIdx.x * 1024 + t * 4;
    int s = 0;
    #pragma unroll
    for (int j = 0; j < 4; ++j) if (base + j < n) s += deg[base + j];
    ts[t] = s;
    __syncthreads();
    #pragma unroll
    for (int off = 128; off >= 1; off >>= 1) {
        if (t < off) ts[t] += ts[t + off];
        __syncthreads();
    }
    if (t == 0) blocksums[blockIdx.x] = ts[0];
}

__global__ void scan_b(const int* __restrict__ blocksums, int* __restrict__ blockoff,
                       int NB, int* __restrict__ rowptr_n) {
    __shared__ int ts[256];
    int t = threadIdx.x;
    int v = (t < NB) ? blocksums[t] : 0;
    ts[t] = v;
    __syncthreads();
    for (int off = 1; off < 256; off <<= 1) {
        int u = (t >= off) ? ts[t - off] : 0;
        __syncthreads();
        ts[t] += u;
        __syncthreads();
    }
    if (t < NB) blockoff[t] = ts[t] - v;
    if (t == 255) *rowptr_n = ts[255];
}

__global__ void scan_c(const int* __restrict__ deg, const int* __restrict__ blockoff,
                       int* __restrict__ rowptr, float* __restrict__ inv_deg, int n) {
    __shared__ int ts[256];
    int t = threadIdx.x;
    int base = blockIdx.x * 1024 + t * 4;
    int d[4];
    int s = 0;
    #pragma unroll
    for (int j = 0; j < 4; ++j) {
        d[j] = (base + j < n) ? deg[base + j] : 0;
        s += d[j];
    }
    ts[t] = s;
    __syncthreads();
    for (int off = 1; off < 256; off <<= 1) {
        int u = (t >= off) ? ts[t - off] : 0;
        __syncthreads();
        ts[t] += u;
        __syncthreads();
    }
    int ex = ts[t] - s + blockoff[blockIdx.x];
    #pragma unroll
    for (int j = 0; j < 4; ++j) {
        if (base + j < n) {
            rowptr[base + j] = ex;
            inv_deg[base + j] = d[j] > 0 ? 1.0f / (float)d[j] : 0.0f;
            ex += d[j];
        }
    }
}

// atomic-free CSR fill: pos = rowptr[dst] + rank (precomputed).
__global__ void fill_kernel(const int* __restrict__ src, const int* __restrict__ dst,
                            const int* __restrict__ rowptr, const int* __restrict__ rank,
                            int* __restrict__ csr, int E) {
    int i = blockIdx.x * blockDim.x + threadIdx.x;
    if (i < E) csr[rowptr[dst[i]] + rank[i]] = src[i];
}

__device__ inline void addq(float* a, uint32_t u0, uint32_t u1, uint32_t u2, uint32_t u3) {
    uint32_t u[4] = {u0, u1, u2, u3};
    #pragma unroll
    for (int i = 0; i < 4; ++i) {
        a[2 * i]     += __uint_as_float(u[i] << 16);
        a[2 * i + 1] += __uint_as_float(u[i] & 0xffff0000u);
    }
}

// bf16 gather aggregation: C/8 lanes per node, 16B (8 bf16) per lane.
// 8-way neighbor unroll (16 rows in flight per wave); sequential addq order
// preserved -> bit-identical results to the 4-way version.
template<int C>
__global__ void agg_bf16(const uint16_t* __restrict__ hb, const int* __restrict__ rowptr,
                         const int* __restrict__ csr, const float* __restrict__ inv_deg,
                         uint16_t* __restrict__ aggb, int n) {
    constexpr int LPN = C / 8;
    constexpr int NPB = 256 / LPN;
    int node = blockIdx.x * NPB + (int)(threadIdx.x / LPN);
    if (node >= n) return;
    int sub = threadIdx.x % LPN;
    int b = rowptr[node], e = rowptr[node + 1];
    float acc[8] = {0.f, 0.f, 0.f, 0.f, 0.f, 0.f, 0.f, 0.f};
    const uint4* h4 = (const uint4*)hb;
    int k = b;
    for (; k + 7 < e; k += 8) {
        int s0 = csr[k],     s1 = csr[k + 1], s2 = csr[k + 2], s3 = csr[k + 3];
        int s4 = csr[k + 4], s5 = csr[k + 5], s6 = csr[k + 6], s7 = csr[k + 7];
        uint4 q0 = h4[(size_t)s0 * LPN + sub];
        uint4 q1 = h4[(size_t)s1 * LPN + sub];
        uint4 q2 = h4[(size_t)s2 * LPN + sub];
        uint4 q3 = h4[(size_t)s3 * LPN + sub];
        uint4 q4 = h4[(size_t)s4 * LPN + sub];
        uint4 q5 = h4[(size_t)s5 * LPN + sub];
        uint4 q6 = h4[(size_t)s6 * LPN + sub];
        uint4 q7 = h4[(size_t)s7 * LPN + sub];
        addq(acc, q0.x, q0.y, q0.z, q0.w);
        addq(acc, q1.x, q1.y, q1.z, q1.w);
        addq(acc, q2.x, q2.y, q2.z, q2.w);
        addq(acc, q3.x, q3.y, q3.z, q3.w);
        addq(acc, q4.x, q4.y, q4.z, q4.w);
        addq(acc, q5.x, q5.y, q5.z, q5.w);
        addq(acc, q6.x, q6.y, q6.z, q6.w);
        addq(acc, q7.x, q7.y, q7.z, q7.w);
    }
    for (; k + 3 < e; k += 4) {
        int s0 = csr[k], s1 = csr[k + 1], s2 = csr[k + 2], s3 = csr[k + 3];
        uint4 q0 = h4[(size_t)s0 * LPN + sub];
        uint4 q1 = h4[(size_t)s1 * LPN + sub];
        uint4 q2 = h4[(size_t)s2 * LPN + sub];
        uint4 q3 = h4[(size_t)s3 * LPN + sub];
        addq(acc, q0.x, q0.y, q0.z, q0.w);
        addq(acc, q1.x, q1.y, q1.z, q1.w);
        addq(acc, q2.x, q2.y, q2.z, q2.w);
        addq(acc, q3.x, q3.y, q3.z, q3.w);
    }
    for (; k < e; ++k) {
        uint4 q = h4[(size_t)csr[k] * LPN + sub];
        addq(acc, q.x, q.y, q.z, q.w);
    }
    float id = inv_deg[node];
    bf16x8 o;
    #pragma unroll
    for (int j = 0; j < 8; ++j) o[j] = (__bf16)(acc[j] * id);
    *(bf16x8*)(aggb + (size_t)node * C + sub * 8) = o;
}

__device__ inline uint16_t f2bf(float f) {
    __bf16 h = (__bf16)f;
    union { __bf16 b; uint16_t u; } c;
    c.b = h;
    return c.u;
}

// Fused GEMM (R15-proven): out = relu([A1 | A2] @ W + bias), A/W bf16.
// 128 rows x 128 cols per block; m97 pipeline, BK=32, single-plane W.
template<int K1>
__global__ __launch_bounds__(256, 3)
void gemm_mfma(const uint16_t* __restrict__ A1, const uint16_t* __restrict__ A2,
               const uint8_t* __restrict__ Wpre, const float* __restrict__ bias,
               float* __restrict__ out, uint16_t* __restrict__ outb, int n) {
    constexpr int S1 = K1 / 32;
    constexpr int NT = 2 * S1;          // 8 or 16
    __shared__ __align__(16) uint8_t ldsA[2][8192];   // 128 rows x 64B
    __shared__ __align__(16) uint8_t ldsW[2][8192];   // 128 cols x 64B (frag-major)

    const int tid = threadIdx.x;
    const int l = tid & 63;
    const int w = tid >> 6;
    const int lr = l & 15;
    const int lg = l >> 4;
    const int row0 = (blockIdx.x >> 1) * 128;
    const int cb = blockIdx.x & 1;       // col half (128 cols)
    const int wr = w & 1;                // wave row half (64 rows)
    const int cw = w >> 1;               // wave col group (64 cols)

    f32x4 acc[4][4];
    #pragma unroll
    for (int mt = 0; mt < 4; ++mt)
        #pragma unroll
        for (int nt = 0; nt < 4; ++nt)
            acc[mt][nt] = (f32x4)(0.f);

    const int key = (lr >> 1) & 3;
    uint32_t abyte[4];
    #pragma unroll
    for (int mt = 0; mt < 4; ++mt)
        abyte[mt] = (uint32_t)((wr * 64 + mt * 16 + lr) * 64 + ((lg ^ key) << 4));
    uint32_t wrbyte[4];
    #pragma unroll
    for (int nt = 0; nt < 4; ++nt)
        wrbyte[nt] = (uint32_t)((cw * 4 + nt) * 1024 + l * 16);

    auto stage = [&](int s, int buf) {
        const uint16_t* __restrict__ A = (s < S1) ? A1 : A2;
        int kl = ((s < S1) ? s : s - S1) * 32;
        #pragma unroll
        for (int i = 0; i < 2; ++i) {
            int b = w * 2 + i;                     // A block 0..7
            int r = b * 16 + (l >> 2);             // row 0..127
            int kq = (l & 3) ^ ((r >> 1) & 3);     // pre-swizzled source k-quad
            gload_lds16(A + (size_t)(row0 + r) * K1 + kl + kq * 8,
                        &ldsA[buf][b * 1024]);
        }
        const uint8_t* __restrict__ Ws = Wpre + (size_t)s * 16384 + (size_t)cb * 8192;
        #pragma unroll
        for (int i = 0; i < 2; ++i) {
            int b = w * 2 + i;                     // W block 0..7
            gload_lds16(Ws + b * 1024 + l * 16, &ldsW[buf][b * 1024]);
        }
    };

    auto domfma = [&](int buf) {
        bf16x8 bh[4];
        #pragma unroll
        for (int nt = 0; nt < 4; ++nt)
            bh[nt] = *(const bf16x8*)(&ldsW[buf][wrbyte[nt]]);
        #pragma unroll
        for (int mt = 0; mt < 4; ++mt) {
            bf16x8 a = *(const bf16x8*)(&ldsA[buf][abyte[mt]]);
            #pragma unroll
            for (int nt = 0; nt < 4; ++nt)
                acc[mt][nt] = __builtin_amdgcn_mfma_f32_16x16x32_bf16(a, bh[nt], acc[mt][nt], 0, 0, 0);
        }
    };

    stage(0, 0);
    __syncthreads();
    #pragma unroll 1
    for (int s = 0; s < NT; ++s) {
        int buf = s & 1;
        if (s + 1 < NT) stage(s + 1, buf ^ 1);   // in flight over MFMAs
        domfma(buf);
        __syncthreads();
    }

    #pragma unroll
    for (int nt = 0; nt < 4; ++nt) {
        int col = cb * 128 + cw * 64 + nt * 16 + lr;
        float bv = bias[col];
        #pragma unroll
        for (int mt = 0; mt < 4; ++mt) {
            #pragma unroll
            for (int rr = 0; rr < 4; ++rr) {
                int grow = row0 + wr * 64 + mt * 16 + lg * 4 + rr;
                if (grow < n) {
                    float v = fmaxf(acc[mt][nt][rr] + bv, 0.f);
                    if (out)  out[(size_t)grow * 256 + col] = v;
                    if (outb) outb[(size_t)grow * 256 + col] = f2bf(v);
                }
            }
        }
    }
}

extern "C" void kernel_launch(void* const* d_in, const int* in_sizes, int n_in,
                              void* d_out, int out_size, void* d_ws, size_t ws_size,
                              hipStream_t stream) {
    const float* x   = (const float*)d_in[0];
    const int* edge  = (const int*)d_in[1];
    const float* Wl0 = (const float*)d_in[2];
    const float* bl0 = (const float*)d_in[3];
    const float* Wr0 = (const float*)d_in[4];
    const float* Wl1 = (const float*)d_in[5];
    const float* bl1 = (const float*)d_in[6];
    const float* Wr1 = (const float*)d_in[7];
    const float* Wl2 = (const float*)d_in[8];
    const float* bl2 = (const float*)d_in[9];
    const float* Wr2 = (const float*)d_in[10];

    int n = in_sizes[0] / 128;   // 50000
    int E = in_sizes[1] / 2;     // 800000
    int npad = n + 128;
    const int* src = edge;
    const int* dst = edge + E;

    char* wptr = (char*)d_ws;
    auto alloc = [&](size_t bytes) { char* p = wptr; wptr += align_up(bytes, 256); return p; };
    int*      deg    = (int*)alloc((size_t)n * 4);
    int*      rowptr = (int*)alloc(((size_t)n + 1) * 4);
    int*      rank   = (int*)alloc((size_t)E * 4);
    int*      csr    = (int*)alloc((size_t)E * 4);
    float*    invd   = (float*)alloc((size_t)n * 4);
    int*      bsums  = (int*)alloc(256 * 4);
    int*      boff   = (int*)alloc(256 * 4);
    uint8_t*  Wp0    = (uint8_t*)alloc(8 * 16384);
    uint8_t*  Wp1    = (uint8_t*)alloc(16 * 16384);
    uint8_t*  Wp2    = (uint8_t*)alloc(16 * 16384);
    uint16_t* xb     = (uint16_t*)alloc((size_t)npad * 128 * 2);
    uint16_t* aggb   = (uint16_t*)alloc((size_t)npad * 256 * 2);
    uint16_t* h0b    = (uint16_t*)alloc((size_t)npad * 256 * 2);
    uint16_t* h1b    = (uint16_t*)alloc((size_t)npad * 256 * 2);

    int NB = (n + 1023) / 1024;
    int cx = n * 128;
    int nb1 = (E + 255) / 256;
    int nb2 = (cx / 8 + 255) / 256;

    hipMemsetAsync(deg, 0, (size_t)n * 4, stream);
    prep_all<<<nb1 + nb2 + 320, 256, 0, stream>>>(dst, deg, rank, E, nb1,
                                                  x, xb, cx, nb2,
                                                  Wl0, Wr0, Wp0, Wl1, Wr1, Wp1,
                                                  Wl2, Wr2, Wp2);
    scan_a<<<NB, 256, 0, stream>>>(deg, bsums, n);
    scan_b<<<1, 256, 0, stream>>>(bsums, boff, NB, rowptr + n);
    scan_c<<<NB, 256, 0, stream>>>(deg, boff, rowptr, invd, n);
    fill_kernel<<<(E + 255) / 256, 256, 0, stream>>>(src, dst, rowptr, rank, csr, E);

    int gemm_grid = ((n + 127) / 128) * 2;   // 782
    // layer 0: C=128 -> 256
    agg_bf16<128><<<(n + 15) / 16, 256, 0, stream>>>(xb, rowptr, csr, invd, aggb, n);
    gemm_mfma<128><<<gemm_grid, 256, 0, stream>>>(aggb, xb, Wp0, bl0, (float*)nullptr, h0b, n);
    // layer 1: 256 -> 256
    agg_bf16<256><<<(n + 7) / 8, 256, 0, stream>>>(h0b, rowptr, csr, invd, aggb, n);
    gemm_mfma<256><<<gemm_grid, 256, 0, stream>>>(aggb, h0b, Wp1, bl1, (float*)nullptr, h1b, n);
    // layer 2: 256 -> 256 (fp32 output to d_out)
    agg_bf16<256><<<(n + 7) / 8, 256, 0, stream>>>(h1b, rowptr, csr, invd, aggb, n);
    gemm_mfma<256><<<gemm_grid, 256, 0, stream>>>(aggb, h1b, Wp2, bl2, (float*)d_out, (uint16_t*)nullptr, n);
}

// Round 20
// 286.692 us; speedup vs baseline: 1.3515x; 1.0370x over previous
//
#include <hip/hip_runtime.h>
#include <cstdint>
#include <cstddef>

// GraphSAGE 3-layer, mean aggregation.
// R20: T1 XCD-aware bijective block swizzle on the GEMM (m204 formula; 782%8=6
// so the naive %8 swizzle is non-bijective). Logical blocks 2k/2k+1 share a
// 128-row A panel; HW round-robin was splitting them across XCDs, so every
// panel was L2-filled twice from L3. Swizzle maps consecutive logical blocks
// to the same XCD -> A fill traffic halves. No arithmetic change.
// R19 lesson kept: agg is MSHR/compulsory-bound (8-way unroll = no change);
// agg untouched. Kept: rank-from-degree fill (R18), fused prep (R19),
// 128x128 BK=32 single-plane-W gemm (R15), 3-phase scan (R3).

typedef __bf16 bf16x8 __attribute__((ext_vector_type(8)));
typedef __bf16 bf16x4 __attribute__((ext_vector_type(4)));
typedef float  f32x4  __attribute__((ext_vector_type(4)));

static inline size_t align_up(size_t x, size_t a) { return (x + a - 1) / a * a; }

__device__ __forceinline__ void gload_lds16(const void* g, void* l) {
    __builtin_amdgcn_global_load_lds(
        (const __attribute__((address_space(1))) void*)g,
        (__attribute__((address_space(3))) void*)l, 16, 0, 0);
}

// ---- fused prep: [0,nb1) deg+rank | [nb1,nb1+nb2) x->bf16 | rest convert_w ----
__global__ void prep_all(const int* __restrict__ dst, int* __restrict__ deg,
                         int* __restrict__ rank, int E, int nb1,
                         const float* __restrict__ x, uint16_t* __restrict__ xb,
                         int cx, int nb2,
                         const float* __restrict__ Wl0, const float* __restrict__ Wr0,
                         uint8_t* __restrict__ Wp0,
                         const float* __restrict__ Wl1, const float* __restrict__ Wr1,
                         uint8_t* __restrict__ Wp1,
                         const float* __restrict__ Wl2, const float* __restrict__ Wr2,
                         uint8_t* __restrict__ Wp2) {
    int bid = blockIdx.x;
    if (bid < nb1) {
        int i = bid * 256 + threadIdx.x;
        if (i < E) rank[i] = atomicAdd(&deg[dst[i]], 1);
        return;
    }
    bid -= nb1;
    if (bid < nb2) {
        int i = (bid * 256 + threadIdx.x) * 8;
        if (i >= cx) return;
        float4 v0 = *(const float4*)(x + i);
        float4 v1 = *(const float4*)(x + i + 4);
        bf16x8 o;
        o[0] = (__bf16)v0.x; o[1] = (__bf16)v0.y; o[2] = (__bf16)v0.z; o[3] = (__bf16)v0.w;
        o[4] = (__bf16)v1.x; o[5] = (__bf16)v1.y; o[6] = (__bf16)v1.z; o[7] = (__bf16)v1.w;
        *(bf16x8*)(xb + i) = o;
        return;
    }
    bid -= nb2;   // 0..319
    const float *Wl, *Wr;
    uint8_t* Wpre;
    int K1, kbase;
    if (bid < 64)       { Wl = Wl0; Wr = Wr0; Wpre = Wp0; K1 = 128; kbase = bid * 4; }
    else if (bid < 192) { Wl = Wl1; Wr = Wr1; Wpre = Wp1; K1 = 256; kbase = (bid - 64) * 4; }
    else                { Wl = Wl2; Wr = Wr2; Wpre = Wp2; K1 = 256; kbase = (bid - 192) * 4; }
    int c = threadIdx.x;
    bf16x4 hi4;
    #pragma unroll
    for (int j = 0; j < 4; ++j) {
        int k = kbase + j;
        float w = (k < K1) ? Wl[(size_t)k * 256 + c] : Wr[(size_t)(k - K1) * 256 + c];
        hi4[j] = (__bf16)w;
    }
    int s = kbase >> 5;
    int kk = kbase & 31;
    int lane = (c & 15) + ((kk >> 3) << 4);
    uint32_t byte = (uint32_t)(c >> 4) * 1024 + (uint32_t)lane * 16 + (uint32_t)(kk & 7) * 2;
    *(bf16x4*)(Wpre + (size_t)s * 16384 + byte) = hi4;
}

// ---- 3-phase scan: deg -> rowptr (exclusive), inv_deg ----
__global__ void scan_a(const int* __restrict__ deg, int* __restrict__ blocksums, int n) {
    __shared__ int ts[256];
    int t = threadIdx.x;
    int base = blockIdx.x * 1024 + t * 4;
    int s = 0;
    #pragma unroll
    for (int j = 0; j < 4; ++j) if (base + j < n) s += deg[base + j];
    ts[t] = s;
    __syncthreads();
    #pragma unroll
    for (int off = 128; off >= 1; off >>= 1) {
        if (t < off) ts[t] += ts[t + off];
        __syncthreads();
    }
    if (t == 0) blocksums[blockIdx.x] = ts[0];
}

__global__ void scan_b(const int* __restrict__ blocksums, int* __restrict__ blockoff,
                       int NB, int* __restrict__ rowptr_n) {
    __shared__ int ts[256];
    int t = threadIdx.x;
    int v = (t < NB) ? blocksums[t] : 0;
    ts[t] = v;
    __syncthreads();
    for (int off = 1; off < 256; off <<= 1) {
        int u = (t >= off) ? ts[t - off] : 0;
        __syncthreads();
        ts[t] += u;
        __syncthreads();
    }
    if (t < NB) blockoff[t] = ts[t] - v;
    if (t == 255) *rowptr_n = ts[255];
}

__global__ void scan_c(const int* __restrict__ deg, const int* __restrict__ blockoff,
                       int* __restrict__ rowptr, float* __restrict__ inv_deg, int n) {
    __shared__ int ts[256];
    int t = threadIdx.x;
    int base = blockIdx.x * 1024 + t * 4;
    int d[4];
    int s = 0;
    #pragma unroll
    for (int j = 0; j < 4; ++j) {
        d[j] = (base + j < n) ? deg[base + j] : 0;
        s += d[j];
    }
    ts[t] = s;
    __syncthreads();
    for (int off = 1; off < 256; off <<= 1) {
        int u = (t >= off) ? ts[t - off] : 0;
        __syncthreads();
        ts[t] += u;
        __syncthreads();
    }
    int ex = ts[t] - s + blockoff[blockIdx.x];
    #pragma unroll
    for (int j = 0; j < 4; ++j) {
        if (base + j < n) {
            rowptr[base + j] = ex;
            inv_deg[base + j] = d[j] > 0 ? 1.0f / (float)d[j] : 0.0f;
            ex += d[j];
        }
    }
}

// atomic-free CSR fill: pos = rowptr[dst] + rank (precomputed).
__global__ void fill_kernel(const int* __restrict__ src, const int* __restrict__ dst,
                            const int* __restrict__ rowptr, const int* __restrict__ rank,
                            int* __restrict__ csr, int E) {
    int i = blockIdx.x * blockDim.x + threadIdx.x;
    if (i < E) csr[rowptr[dst[i]] + rank[i]] = src[i];
}

__device__ inline void addq(float* a, uint32_t u0, uint32_t u1, uint32_t u2, uint32_t u3) {
    uint32_t u[4] = {u0, u1, u2, u3};
    #pragma unroll
    for (int i = 0; i < 4; ++i) {
        a[2 * i]     += __uint_as_float(u[i] << 16);
        a[2 * i + 1] += __uint_as_float(u[i] & 0xffff0000u);
    }
}

// bf16 gather aggregation: C/8 lanes per node, 16B (8 bf16) per lane.
template<int C>
__global__ void agg_bf16(const uint16_t* __restrict__ hb, const int* __restrict__ rowptr,
                         const int* __restrict__ csr, const float* __restrict__ inv_deg,
                         uint16_t* __restrict__ aggb, int n) {
    constexpr int LPN = C / 8;
    constexpr int NPB = 256 / LPN;
    int node = blockIdx.x * NPB + (int)(threadIdx.x / LPN);
    if (node >= n) return;
    int sub = threadIdx.x % LPN;
    int b = rowptr[node], e = rowptr[node + 1];
    float acc[8] = {0.f, 0.f, 0.f, 0.f, 0.f, 0.f, 0.f, 0.f};
    const uint4* h4 = (const uint4*)hb;
    int k = b;
    for (; k + 3 < e; k += 4) {
        int s0 = csr[k], s1 = csr[k + 1], s2 = csr[k + 2], s3 = csr[k + 3];
        uint4 q0 = h4[(size_t)s0 * LPN + sub];
        uint4 q1 = h4[(size_t)s1 * LPN + sub];
        uint4 q2 = h4[(size_t)s2 * LPN + sub];
        uint4 q3 = h4[(size_t)s3 * LPN + sub];
        addq(acc, q0.x, q0.y, q0.z, q0.w);
        addq(acc, q1.x, q1.y, q1.z, q1.w);
        addq(acc, q2.x, q2.y, q2.z, q2.w);
        addq(acc, q3.x, q3.y, q3.z, q3.w);
    }
    for (; k < e; ++k) {
        uint4 q = h4[(size_t)csr[k] * LPN + sub];
        addq(acc, q.x, q.y, q.z, q.w);
    }
    float id = inv_deg[node];
    bf16x8 o;
    #pragma unroll
    for (int j = 0; j < 8; ++j) o[j] = (__bf16)(acc[j] * id);
    *(bf16x8*)(aggb + (size_t)node * C + sub * 8) = o;
}

__device__ inline uint16_t f2bf(float f) {
    __bf16 h = (__bf16)f;
    union { __bf16 b; uint16_t u; } c;
    c.b = h;
    return c.u;
}

// Fused GEMM (R15-proven): out = relu([A1 | A2] @ W + bias), A/W bf16.
// 128 rows x 128 cols per block; m97 pipeline, BK=32, single-plane W.
// NEW: bijective XCD swizzle (m204): consecutive LOGICAL blocks (which share
// an A panel) land on the same XCD -> A panel L2-filled once per XCD, not twice.
template<int K1>
__global__ __launch_bounds__(256, 3)
void gemm_mfma(const uint16_t* __restrict__ A1, const uint16_t* __restrict__ A2,
               const uint8_t* __restrict__ Wpre, const float* __restrict__ bias,
               float* __restrict__ out, uint16_t* __restrict__ outb, int n, int nwg) {
    constexpr int S1 = K1 / 32;
    constexpr int NT = 2 * S1;          // 8 or 16
    __shared__ __align__(16) uint8_t ldsA[2][8192];   // 128 rows x 64B
    __shared__ __align__(16) uint8_t ldsW[2][8192];   // 128 cols x 64B (frag-major)

    // m204 bijective XCD swizzle: HW assigns wgid w -> XCD w%8 (round-robin).
    // logical = base(x) + w/8 with x = w%8 gives XCD x a contiguous logical
    // chunk; bijective for any nwg.
    int wid = blockIdx.x;
    int q = nwg >> 3, r = nwg & 7;
    int xcd = wid & 7, idx = wid >> 3;
    int basex = (xcd < r) ? xcd * (q + 1) : r * (q + 1) + (xcd - r) * q;
    int logical = basex + idx;

    const int tid = threadIdx.x;
    const int l = tid & 63;
    const int w = tid >> 6;
    const int lr = l & 15;
    const int lg = l >> 4;
    const int row0 = (logical >> 1) * 128;
    const int cb = logical & 1;          // col half (128 cols)
    const int wr = w & 1;                // wave row half (64 rows)
    const int cw = w >> 1;               // wave col group (64 cols)

    f32x4 acc[4][4];
    #pragma unroll
    for (int mt = 0; mt < 4; ++mt)
        #pragma unroll
        for (int nt = 0; nt < 4; ++nt)
            acc[mt][nt] = (f32x4)(0.f);

    const int key = (lr >> 1) & 3;
    uint32_t abyte[4];
    #pragma unroll
    for (int mt = 0; mt < 4; ++mt)
        abyte[mt] = (uint32_t)((wr * 64 + mt * 16 + lr) * 64 + ((lg ^ key) << 4));
    uint32_t wrbyte[4];
    #pragma unroll
    for (int nt = 0; nt < 4; ++nt)
        wrbyte[nt] = (uint32_t)((cw * 4 + nt) * 1024 + l * 16);

    auto stage = [&](int s, int buf) {
        const uint16_t* __restrict__ A = (s < S1) ? A1 : A2;
        int kl = ((s < S1) ? s : s - S1) * 32;
        #pragma unroll
        for (int i = 0; i < 2; ++i) {
            int b = w * 2 + i;                     // A block 0..7
            int r2 = b * 16 + (l >> 2);            // row 0..127
            int kq = (l & 3) ^ ((r2 >> 1) & 3);    // pre-swizzled source k-quad
            gload_lds16(A + (size_t)(row0 + r2) * K1 + kl + kq * 8,
                        &ldsA[buf][b * 1024]);
        }
        const uint8_t* __restrict__ Ws = Wpre + (size_t)s * 16384 + (size_t)cb * 8192;
        #pragma unroll
        for (int i = 0; i < 2; ++i) {
            int b = w * 2 + i;                     // W block 0..7
            gload_lds16(Ws + b * 1024 + l * 16, &ldsW[buf][b * 1024]);
        }
    };

    auto domfma = [&](int buf) {
        bf16x8 bh[4];
        #pragma unroll
        for (int nt = 0; nt < 4; ++nt)
            bh[nt] = *(const bf16x8*)(&ldsW[buf][wrbyte[nt]]);
        #pragma unroll
        for (int mt = 0; mt < 4; ++mt) {
            bf16x8 a = *(const bf16x8*)(&ldsA[buf][abyte[mt]]);
            #pragma unroll
            for (int nt = 0; nt < 4; ++nt)
                acc[mt][nt] = __builtin_amdgcn_mfma_f32_16x16x32_bf16(a, bh[nt], acc[mt][nt], 0, 0, 0);
        }
    };

    stage(0, 0);
    __syncthreads();
    #pragma unroll 1
    for (int s = 0; s < NT; ++s) {
        int buf = s & 1;
        if (s + 1 < NT) stage(s + 1, buf ^ 1);   // in flight over MFMAs
        domfma(buf);
        __syncthreads();
    }

    #pragma unroll
    for (int nt = 0; nt < 4; ++nt) {
        int col = cb * 128 + cw * 64 + nt * 16 + lr;
        float bv = bias[col];
        #pragma unroll
        for (int mt = 0; mt < 4; ++mt) {
            #pragma unroll
            for (int rr = 0; rr < 4; ++rr) {
                int grow = row0 + wr * 64 + mt * 16 + lg * 4 + rr;
                if (grow < n) {
                    float v = fmaxf(acc[mt][nt][rr] + bv, 0.f);
                    if (out)  out[(size_t)grow * 256 + col] = v;
                    if (outb) outb[(size_t)grow * 256 + col] = f2bf(v);
                }
            }
        }
    }
}

extern "C" void kernel_launch(void* const* d_in, const int* in_sizes, int n_in,
                              void* d_out, int out_size, void* d_ws, size_t ws_size,
                              hipStream_t stream) {
    const float* x   = (const float*)d_in[0];
    const int* edge  = (const int*)d_in[1];
    const float* Wl0 = (const float*)d_in[2];
    const float* bl0 = (const float*)d_in[3];
    const float* Wr0 = (const float*)d_in[4];
    const float* Wl1 = (const float*)d_in[5];
    const float* bl1 = (const float*)d_in[6];
    const float* Wr1 = (const float*)d_in[7];
    const float* Wl2 = (const float*)d_in[8];
    const float* bl2 = (const float*)d_in[9];
    const float* Wr2 = (const float*)d_in[10];

    int n = in_sizes[0] / 128;   // 50000
    int E = in_sizes[1] / 2;     // 800000
    int npad = n + 128;
    const int* src = edge;
    const int* dst = edge + E;

    char* wptr = (char*)d_ws;
    auto alloc = [&](size_t bytes) { char* p = wptr; wptr += align_up(bytes, 256); return p; };
    int*      deg    = (int*)alloc((size_t)n * 4);
    int*      rowptr = (int*)alloc(((size_t)n + 1) * 4);
    int*      rank   = (int*)alloc((size_t)E * 4);
    int*      csr    = (int*)alloc((size_t)E * 4);
    float*    invd   = (float*)alloc((size_t)n * 4);
    int*      bsums  = (int*)alloc(256 * 4);
    int*      boff   = (int*)alloc(256 * 4);
    uint8_t*  Wp0    = (uint8_t*)alloc(8 * 16384);
    uint8_t*  Wp1    = (uint8_t*)alloc(16 * 16384);
    uint8_t*  Wp2    = (uint8_t*)alloc(16 * 16384);
    uint16_t* xb     = (uint16_t*)alloc((size_t)npad * 128 * 2);
    uint16_t* aggb   = (uint16_t*)alloc((size_t)npad * 256 * 2);
    uint16_t* h0b    = (uint16_t*)alloc((size_t)npad * 256 * 2);
    uint16_t* h1b    = (uint16_t*)alloc((size_t)npad * 256 * 2);

    int NB = (n + 1023) / 1024;
    int cx = n * 128;
    int nb1 = (E + 255) / 256;
    int nb2 = (cx / 8 + 255) / 256;

    hipMemsetAsync(deg, 0, (size_t)n * 4, stream);
    prep_all<<<nb1 + nb2 + 320, 256, 0, stream>>>(dst, deg, rank, E, nb1,
                                                  x, xb, cx, nb2,
                                                  Wl0, Wr0, Wp0, Wl1, Wr1, Wp1,
                                                  Wl2, Wr2, Wp2);
    scan_a<<<NB, 256, 0, stream>>>(deg, bsums, n);
    scan_b<<<1, 256, 0, stream>>>(bsums, boff, NB, rowptr + n);
    scan_c<<<NB, 256, 0, stream>>>(deg, boff, rowptr, invd, n);
    fill_kernel<<<(E + 255) / 256, 256, 0, stream>>>(src, dst, rowptr, rank, csr, E);

    int gemm_grid = ((n + 127) / 128) * 2;   // 782
    // layer 0: C=128 -> 256
    agg_bf16<128><<<(n + 15) / 16, 256, 0, stream>>>(xb, rowptr, csr, invd, aggb, n);
    gemm_mfma<128><<<gemm_grid, 256, 0, stream>>>(aggb, xb, Wp0, bl0, (float*)nullptr, h0b, n, gemm_grid);
    // layer 1: 256 -> 256
    agg_bf16<256><<<(n + 7) / 8, 256, 0, stream>>>(h0b, rowptr, csr, invd, aggb, n);
    gemm_mfma<256><<<gemm_grid, 256, 0, stream>>>(aggb, h0b, Wp1, bl1, (float*)nullptr, h1b, n, gemm_grid);
    // layer 2: 256 -> 256 (fp32 output to d_out)
    agg_bf16<256><<<(n + 7) / 8, 256, 0, stream>>>(h1b, rowptr, csr, invd, aggb, n);
    gemm_mfma<256><<<gemm_grid, 256, 0, stream>>>(aggb, h1b, Wp2, bl2, (float*)d_out, (uint16_t*)nullptr, n, gemm_grid);
}